// Round 1
// baseline (2271.586 us; speedup 1.0000x reference)
//
#include <hip/hip_runtime.h>
#include <hip/hip_bf16.h>
#include <math.h>

typedef unsigned short u16;
typedef __attribute__((ext_vector_type(8))) short short8;
typedef __attribute__((ext_vector_type(4))) float f32x4;

static __device__ __forceinline__ u16 f2b(float x) {
  __hip_bfloat16 h = __float2bfloat16(x);
  return *reinterpret_cast<u16*>(&h);
}
static __device__ __forceinline__ float b2f(u16 u) {
  unsigned int v = ((unsigned int)u) << 16;
  float f;
  __builtin_memcpy(&f, &v, 4);
  return f;
}

// ---------------- conversion kernels ----------------

__global__ void cvt_flat(const float* __restrict__ s, u16* __restrict__ d, long n) {
  long i = ((long)blockIdx.x * 256 + threadIdx.x) * 4;
  long stride = (long)gridDim.x * 1024;
  for (; i < n; i += stride) {
    float4 v = *(const float4*)(s + i);
    ushort4 o;
    o.x = f2b(v.x); o.y = f2b(v.y); o.z = f2b(v.z); o.w = f2b(v.w);
    *(ushort4*)(d + i) = o;
  }
}

// d[r*(1<<lshift)+c] = bf16(s[r*sstride + soff + c])
__global__ void cvt_strided(const float* __restrict__ s, u16* __restrict__ d,
                            long total, int lshift, long sstride, long soff) {
  long i = (long)blockIdx.x * 256 + threadIdx.x;
  long step = (long)gridDim.x * 256;
  long mask = (1L << lshift) - 1;
  for (; i < total; i += step) {
    long r = i >> lshift;
    long c = i & mask;
    d[i] = f2b(s[r * sstride + soff + c]);
  }
}

// Xbf row m = t*32+b  <-  gt[b, t, :]  (t<31); rows >= 992 zeroed
__global__ void cvt_x(const float* __restrict__ gt, u16* __restrict__ d) {
  long idx = (long)blockIdx.x * 256 + threadIdx.x;  // 1024*512 total
  if (idx >= 1024L * 512) return;
  long m = idx >> 9;
  int k = (int)(idx & 511);
  if (m < 992) {
    int tt = (int)(m >> 5), b = (int)(m & 31);
    d[idx] = f2b(gt[((long)b * 32 + tt) * 512 + k]);
  } else {
    d[idx] = 0;  // +0.0 bf16
  }
}

// ---------------- generic MFMA GEMM: C = A(M,K) * B(N,K)^T ----------------
// A: (Mp x K) bf16 row-major, lda=K.  B: (N x K) bf16 row-major, ldb=K.
// 128x128 tile, BK=32, 4 waves, each wave 64x64 (4x4 frags of 16x16x32).
// EPI: 0=bf16 out, no bias (FW)
//      1=f32 out, tanh(acc+bias)*pw (wvf)
//      2=f32 out, acc+bias, guard row<M (GX)
//      3=f32 out, remap row (t*32+b)->(b*31+t), +bias, guard (logits)
//      4=split: col<256 -> tanh(acc+bias)->C0 (uh, ld 256); else acc+bias->C1 (gh, ld 3072); guard row<M
template<int EPI>
__global__ __launch_bounds__(256)
void gemm_bt(const u16* __restrict__ A, const u16* __restrict__ B,
             void* __restrict__ C0, void* __restrict__ C1,
             const float* __restrict__ bias, const float* __restrict__ pw,
             int M, int N, int K) {
  __shared__ u16 As[4096];
  __shared__ u16 Bs[4096];
  const int tid = threadIdx.x;
  const int lane = tid & 63, wid = tid >> 6;
  const long row0 = (long)blockIdx.y * 128;
  const long col0 = (long)blockIdx.x * 128;
  const int wm = (wid >> 1) * 64, wn = (wid & 1) * 64;
  const int fr = lane & 15, fq = lane >> 4;
  const int sr = wid * 16 + (lane >> 2);
  const int sc = (lane & 3) * 8;

  const u16* Ag0 = A + (row0 + sr) * (long)K + sc;
  const u16* Ag1 = Ag0 + 64 * (long)K;
  const u16* Bg0 = B + (col0 + sr) * (long)K + sc;
  const u16* Bg1 = Bg0 + 64 * (long)K;

  u16* AsW0 = &As[wid * 512];
  u16* AsW1 = &As[2048 + wid * 512];
  u16* BsW0 = &Bs[wid * 512];
  u16* BsW1 = &Bs[2048 + wid * 512];

  f32x4 acc[4][4];
#pragma unroll
  for (int i = 0; i < 4; ++i)
#pragma unroll
    for (int j = 0; j < 4; ++j) acc[i][j] = {0.f, 0.f, 0.f, 0.f};

  for (int k0 = 0; k0 < K; k0 += 32) {
    __builtin_amdgcn_global_load_lds((const __attribute__((address_space(1))) void*)(Ag0 + k0),
                                     (__attribute__((address_space(3))) void*)AsW0, 16, 0, 0);
    __builtin_amdgcn_global_load_lds((const __attribute__((address_space(1))) void*)(Ag1 + k0),
                                     (__attribute__((address_space(3))) void*)AsW1, 16, 0, 0);
    __builtin_amdgcn_global_load_lds((const __attribute__((address_space(1))) void*)(Bg0 + k0),
                                     (__attribute__((address_space(3))) void*)BsW0, 16, 0, 0);
    __builtin_amdgcn_global_load_lds((const __attribute__((address_space(1))) void*)(Bg1 + k0),
                                     (__attribute__((address_space(3))) void*)BsW1, 16, 0, 0);
    __syncthreads();
    short8 af[4], bfv[4];
#pragma unroll
    for (int i = 0; i < 4; ++i) af[i] = *(const short8*)&As[(wm + i * 16 + fr) * 32 + fq * 8];
#pragma unroll
    for (int i = 0; i < 4; ++i) bfv[i] = *(const short8*)&Bs[(wn + i * 16 + fr) * 32 + fq * 8];
#pragma unroll
    for (int i = 0; i < 4; ++i)
#pragma unroll
      for (int j = 0; j < 4; ++j)
        acc[i][j] = __builtin_amdgcn_mfma_f32_16x16x32_bf16(af[i], bfv[j], acc[i][j], 0, 0, 0);
    __syncthreads();
  }

#pragma unroll
  for (int i = 0; i < 4; ++i)
#pragma unroll
    for (int j = 0; j < 4; ++j)
#pragma unroll
      for (int q = 0; q < 4; ++q) {
        long gr = row0 + wm + i * 16 + fq * 4 + q;
        long gc = col0 + wn + j * 16 + fr;
        float v = acc[i][j][q];
        if constexpr (EPI == 0) {
          ((u16*)C0)[gr * (long)N + gc] = f2b(v);
        } else if constexpr (EPI == 1) {
          ((float*)C0)[gr * (long)N + gc] = tanhf(v + bias[gc]) * pw[gc];
        } else if constexpr (EPI == 2) {
          if (gr < M) ((float*)C0)[gr * (long)N + gc] = v + bias[gc];
        } else if constexpr (EPI == 3) {
          if (gr < M) {
            long b = gr & 31, t = gr >> 5;
            ((float*)C0)[(b * 31 + t) * (long)N + gc] = v + bias[gc];
          }
        } else {  // EPI == 4
          if (gr < M) {
            if (gc < 256)
              ((float*)C0)[gr * 256 + gc] = tanhf(v + bias[gc]);
            else
              ((float*)C1)[gr * 3072 + (gc - 256)] = v + bias[gc];
          }
        }
      }
}

// ---------------- per-step attention + GRU (one block per batch row) ----------------
__global__ __launch_bounds__(256)
void step_attn(const float* __restrict__ wvf,   // (32*128, 256) f32: tanh(f V^T + Vb) * Pw
               const float* __restrict__ uh,    // (32, 256) f32
               const u16* __restrict__ FWb,     // (32*128, 3072) bf16: f @ Wm^T
               const float* __restrict__ GX,    // (992, 3072) f32: x Wx^T + b_ih, row = t*32+b
               const float* __restrict__ ghb,   // (32, 3072) f32: h W_hh^T + b_hh
               const float* __restrict__ pb,    // P_b (1,)
               float* __restrict__ h,           // (32, 1024) f32 master state
               u16* __restrict__ hbf,           // (128, 1024) bf16 copy (rows 0..31 used)
               u16* __restrict__ Hbuf,          // (1024, 1024) bf16, row t*32+b
               int t) {
  const int b = blockIdx.x, tid = threadIdx.x;
  __shared__ float uhl[256];
  __shared__ float part[256];
  __shared__ float sc[128];
  __shared__ float redv[2];

  uhl[tid] = uh[b * 256 + tid];
  __syncthreads();

  // scores: s = tid&127, half = tid>>7 handles 128 of the 256 d's
  {
    const int s = tid & 127, hf = tid >> 7;
    const float* wr = wvf + ((long)(b * 128 + s)) * 256 + hf * 128;
    const float* u = &uhl[hf * 128];
    float p = 0.f;
#pragma unroll 4
    for (int d = 0; d < 128; ++d) p += u[d] * wr[d];
    part[tid] = p;
  }
  __syncthreads();
  if (tid < 128) sc[tid] = part[tid] + part[tid + 128] + pb[0];
  __syncthreads();
  if (tid < 64) {
    float m = fmaxf(sc[tid], sc[tid + 64]);
    for (int o = 32; o > 0; o >>= 1) m = fmaxf(m, __shfl_down(m, o));
    if (tid == 0) redv[0] = m;
  }
  __syncthreads();
  float mx = redv[0];
  if (tid < 128) sc[tid] = expf(sc[tid] - mx);
  __syncthreads();
  if (tid < 64) {
    float s2 = sc[tid] + sc[tid + 64];
    for (int o = 32; o > 0; o >>= 1) s2 += __shfl_down(s2, o);
    if (tid == 0) redv[1] = s2;
  }
  __syncthreads();
  const float inv = 1.0f / redv[1];

  // gm[j] for j = g*1024 + tid*4 + q  (g<3, q<4): gate triplets stay in-thread
  float am[3][4] = {{0.f, 0.f, 0.f, 0.f}, {0.f, 0.f, 0.f, 0.f}, {0.f, 0.f, 0.f, 0.f}};
  for (int s = 0; s < 128; ++s) {
    float a = sc[s];
    const u16* fw = FWb + ((long)(b * 128 + s)) * 3072 + tid * 4;
#pragma unroll
    for (int g = 0; g < 3; ++g) {
      ushort4 raw = *(const ushort4*)(fw + g * 1024);
      am[g][0] += a * b2f(raw.x);
      am[g][1] += a * b2f(raw.y);
      am[g][2] += a * b2f(raw.z);
      am[g][3] += a * b2f(raw.w);
    }
  }

  const long gxo = ((long)t * 32 + b) * 3072;
  const long ho = (long)b * 1024;
  const long hro = ((long)t * 32 + b) * 1024;
#pragma unroll
  for (int q = 0; q < 4; ++q) {
    int m = tid * 4 + q;
    float gxr = GX[gxo + m] + am[0][q] * inv;
    float gxz = GX[gxo + 1024 + m] + am[1][q] * inv;
    float gxn = GX[gxo + 2048 + m] + am[2][q] * inv;
    float ghr = ghb[(long)b * 3072 + m];
    float ghz = ghb[(long)b * 3072 + 1024 + m];
    float ghn = ghb[(long)b * 3072 + 2048 + m];
    float r = 1.f / (1.f + expf(-(gxr + ghr)));
    float z = 1.f / (1.f + expf(-(gxz + ghz)));
    float n = tanhf(gxn + r * ghn);
    float hv = h[ho + m];
    float hn2 = (1.f - z) * n + z * hv;
    h[ho + m] = hn2;
    u16 hb = f2b(hn2);
    hbf[ho + m] = hb;
    Hbuf[hro + m] = hb;
  }
}

// ---------------- launcher ----------------

extern "C" void kernel_launch(void* const* d_in, const int* in_sizes, int n_in,
                              void* d_out, int out_size, void* d_ws, size_t ws_size,
                              hipStream_t stream) {
  const float* f    = (const float*)d_in[0];   // (32,128,1024)
  const float* h0   = (const float*)d_in[1];   // (32,1024)
  const float* gt   = (const float*)d_in[2];   // (32,32,512)
  const float* U_w  = (const float*)d_in[4];   // (256,1024)
  const float* U_b  = (const float*)d_in[5];
  const float* V_w  = (const float*)d_in[6];   // (256,1024)
  const float* V_b  = (const float*)d_in[7];
  const float* P_w  = (const float*)d_in[8];   // (1,256)
  const float* P_b  = (const float*)d_in[9];
  const float* W_ih = (const float*)d_in[10];  // (3072,1536)
  const float* b_ih = (const float*)d_in[11];
  const float* W_hh = (const float*)d_in[12];  // (3072,1024)
  const float* b_hh = (const float*)d_in[13];
  const float* dw   = (const float*)d_in[14];  // (32000,1024)
  const float* db   = (const float*)d_in[15];

  char* w = (char*)d_ws;
  auto alloc = [&](size_t bytes) { char* p = w; w += (bytes + 255) & ~255ULL; return p; };

  u16*   fbf   = (u16*)alloc(4096L * 1024 * 2);   // f bf16, row b*128+s
  u16*   VwBf  = (u16*)alloc(256L * 1024 * 2);
  u16*   Wcat  = (u16*)alloc(3328L * 1024 * 2);   // [U_w; W_hh]
  u16*   WxBf  = (u16*)alloc(3072L * 512 * 2);    // W_ih[:, :512]
  u16*   WmBf  = (u16*)alloc(3072L * 1024 * 2);   // W_ih[:, 512:]
  u16*   dwBf  = (u16*)alloc(32000L * 1024 * 2);
  u16*   Xbf   = (u16*)alloc(1024L * 512 * 2);    // row t*32+b
  float* wvf   = (float*)alloc(4096L * 256 * 4);
  float* GX    = (float*)alloc(1024L * 3072 * 4);
  u16*   FWb   = (u16*)alloc(4096L * 3072 * 2);
  float* hf32  = (float*)alloc(32L * 1024 * 4);
  u16*   hbf   = (u16*)alloc(128L * 1024 * 2);
  float* uh    = (float*)alloc(32L * 256 * 4);
  float* ghb   = (float*)alloc(32L * 3072 * 4);
  u16*   Hbuf  = (u16*)alloc(1024L * 1024 * 2);
  float* bcat  = (float*)alloc(3328L * 4);        // [U_b; b_hh]

  auto cvg = [](long n) { long g = (n + 1023) / 1024; return (int)(g > 2048 ? 2048 : g); };

  // conversions / init
  cvt_flat<<<cvg(4194304), 256, 0, stream>>>(f, fbf, 4194304);
  cvt_flat<<<cvg(262144), 256, 0, stream>>>(V_w, VwBf, 262144);
  cvt_flat<<<cvg(262144), 256, 0, stream>>>(U_w, Wcat, 262144);
  cvt_flat<<<cvg(3145728), 256, 0, stream>>>(W_hh, Wcat + 262144L, 3145728);
  cvt_strided<<<2048, 256, 0, stream>>>(W_ih, WxBf, 3072L * 512, 9, 1536, 0);
  cvt_strided<<<2048, 256, 0, stream>>>(W_ih, WmBf, 3072L * 1024, 10, 1536, 512);
  cvt_flat<<<cvg(32768000), 256, 0, stream>>>(dw, dwBf, 32768000);
  cvt_x<<<2048, 256, 0, stream>>>(gt, Xbf);
  cvt_flat<<<cvg(32768), 256, 0, stream>>>(h0, hbf, 32768);
  hipMemcpyAsync(hf32, h0, 32L * 1024 * 4, hipMemcpyDeviceToDevice, stream);
  hipMemcpyAsync(bcat, U_b, 256 * 4, hipMemcpyDeviceToDevice, stream);
  hipMemcpyAsync(bcat + 256, b_hh, 3072 * 4, hipMemcpyDeviceToDevice, stream);

  // loop-invariant GEMMs
  gemm_bt<1><<<dim3(2, 32), 256, 0, stream>>>(fbf, VwBf, wvf, nullptr, V_b, P_w, 4096, 256, 1024);
  gemm_bt<2><<<dim3(24, 8), 256, 0, stream>>>(Xbf, WxBf, GX, nullptr, b_ih, nullptr, 992, 3072, 512);
  gemm_bt<0><<<dim3(24, 32), 256, 0, stream>>>(fbf, WmBf, FWb, nullptr, nullptr, nullptr, 4096, 3072, 1024);

  // recurrence
  for (int t = 0; t < 31; ++t) {
    gemm_bt<4><<<dim3(26, 1), 256, 0, stream>>>(hbf, Wcat, uh, ghb, bcat, nullptr, 32, 3328, 1024);
    step_attn<<<32, 256, 0, stream>>>(wvf, uh, FWb, GX, ghb, P_b, hf32, hbf, Hbuf, t);
  }

  // logits
  gemm_bt<3><<<dim3(250, 8), 256, 0, stream>>>(Hbuf, dwBf, (float*)d_out, nullptr, db, nullptr,
                                               992, 32000, 1024);
}

// Round 2
// 1706.803 us; speedup vs baseline: 1.3309x; 1.3309x over previous
//
#include <hip/hip_runtime.h>
#include <hip/hip_bf16.h>
#include <math.h>

typedef unsigned short u16;
typedef __attribute__((ext_vector_type(8))) short short8;
typedef __attribute__((ext_vector_type(4))) float f32x4;

static __device__ __forceinline__ u16 f2b(float x) {
  __hip_bfloat16 h = __float2bfloat16(x);
  return *reinterpret_cast<u16*>(&h);
}
static __device__ __forceinline__ float b2f(u16 u) {
  unsigned int v = ((unsigned int)u) << 16;
  float f;
  __builtin_memcpy(&f, &v, 4);
  return f;
}

// ---------------- conversion kernels ----------------

__global__ void cvt_flat(const float* __restrict__ s, u16* __restrict__ d, long n) {
  long i = ((long)blockIdx.x * 256 + threadIdx.x) * 4;
  long stride = (long)gridDim.x * 1024;
  for (; i < n; i += stride) {
    float4 v = *(const float4*)(s + i);
    ushort4 o;
    o.x = f2b(v.x); o.y = f2b(v.y); o.z = f2b(v.z); o.w = f2b(v.w);
    *(ushort4*)(d + i) = o;
  }
}

// d[r*(1<<lshift)+c] = bf16(s[r*sstride + soff + c])
__global__ void cvt_strided(const float* __restrict__ s, u16* __restrict__ d,
                            long total, int lshift, long sstride, long soff) {
  long i = (long)blockIdx.x * 256 + threadIdx.x;
  long step = (long)gridDim.x * 256;
  long mask = (1L << lshift) - 1;
  for (; i < total; i += step) {
    long r = i >> lshift;
    long c = i & mask;
    d[i] = f2b(s[r * sstride + soff + c]);
  }
}

// Xbf row m = t*32+b  <-  gt[b, t, :]  (t<31); rows >= 992 zeroed
__global__ void cvt_x(const float* __restrict__ gt, u16* __restrict__ d) {
  long idx = (long)blockIdx.x * 256 + threadIdx.x;  // 1024*512 total
  if (idx >= 1024L * 512) return;
  long m = idx >> 9;
  int k = (int)(idx & 511);
  if (m < 992) {
    int tt = (int)(m >> 5), b = (int)(m & 31);
    d[idx] = f2b(gt[((long)b * 32 + tt) * 512 + k]);
  } else {
    d[idx] = 0;  // +0.0 bf16
  }
}

// ---------------- generic MFMA GEMM: C = A(M,K) * B(N,K)^T ----------------
// 128x128 tile, BK=32, 4 waves, each wave 64x64 (4x4 frags of 16x16x32).
// XCD-aware bijective swizzle applied when gridDim.x*gridDim.y % 8 == 0.
// EPI: 0=bf16 out, no bias (FW)
//      1=f32 out, tanh(acc+bias)*pw (wvf)
//      2=f32 out, acc+bias, guard row<M (GX)
//      3=f32 out, remap row (t*32+b)->(b*31+t), +bias, guard, nontemporal (logits)
template<int EPI>
__global__ __launch_bounds__(256)
void gemm_bt(const u16* __restrict__ A, const u16* __restrict__ B,
             void* __restrict__ C0,
             const float* __restrict__ bias, const float* __restrict__ pw,
             int M, int N, int K) {
  __shared__ u16 As[4096];
  __shared__ u16 Bs[4096];
  const int tid = threadIdx.x;
  const int lane = tid & 63, wid = tid >> 6;

  int gx = gridDim.x;
  int nwg = gx * gridDim.y;
  int wg = blockIdx.y * gx + blockIdx.x;
  if ((nwg & 7) == 0) wg = (wg & 7) * (nwg >> 3) + (wg >> 3);
  const long row0 = (long)(wg / gx) * 128;
  const long col0 = (long)(wg % gx) * 128;

  const int wm = (wid >> 1) * 64, wn = (wid & 1) * 64;
  const int fr = lane & 15, fq = lane >> 4;
  const int sr = wid * 16 + (lane >> 2);
  const int sc = (lane & 3) * 8;

  const u16* Ag0 = A + (row0 + sr) * (long)K + sc;
  const u16* Ag1 = Ag0 + 64 * (long)K;
  const u16* Bg0 = B + (col0 + sr) * (long)K + sc;
  const u16* Bg1 = Bg0 + 64 * (long)K;

  u16* AsW0 = &As[wid * 512];
  u16* AsW1 = &As[2048 + wid * 512];
  u16* BsW0 = &Bs[wid * 512];
  u16* BsW1 = &Bs[2048 + wid * 512];

  f32x4 acc[4][4];
#pragma unroll
  for (int i = 0; i < 4; ++i)
#pragma unroll
    for (int j = 0; j < 4; ++j) acc[i][j] = {0.f, 0.f, 0.f, 0.f};

  for (int k0 = 0; k0 < K; k0 += 32) {
    __builtin_amdgcn_global_load_lds((const __attribute__((address_space(1))) void*)(Ag0 + k0),
                                     (__attribute__((address_space(3))) void*)AsW0, 16, 0, 0);
    __builtin_amdgcn_global_load_lds((const __attribute__((address_space(1))) void*)(Ag1 + k0),
                                     (__attribute__((address_space(3))) void*)AsW1, 16, 0, 0);
    __builtin_amdgcn_global_load_lds((const __attribute__((address_space(1))) void*)(Bg0 + k0),
                                     (__attribute__((address_space(3))) void*)BsW0, 16, 0, 0);
    __builtin_amdgcn_global_load_lds((const __attribute__((address_space(1))) void*)(Bg1 + k0),
                                     (__attribute__((address_space(3))) void*)BsW1, 16, 0, 0);
    __syncthreads();
    short8 af[4], bfv[4];
#pragma unroll
    for (int i = 0; i < 4; ++i) af[i] = *(const short8*)&As[(wm + i * 16 + fr) * 32 + fq * 8];
#pragma unroll
    for (int i = 0; i < 4; ++i) bfv[i] = *(const short8*)&Bs[(wn + i * 16 + fr) * 32 + fq * 8];
#pragma unroll
    for (int i = 0; i < 4; ++i)
#pragma unroll
      for (int j = 0; j < 4; ++j)
        acc[i][j] = __builtin_amdgcn_mfma_f32_16x16x32_bf16(af[i], bfv[j], acc[i][j], 0, 0, 0);
    __syncthreads();
  }

#pragma unroll
  for (int i = 0; i < 4; ++i)
#pragma unroll
    for (int j = 0; j < 4; ++j)
#pragma unroll
      for (int q = 0; q < 4; ++q) {
        long gr = row0 + wm + i * 16 + fq * 4 + q;
        long gc = col0 + wn + j * 16 + fr;
        float v = acc[i][j][q];
        if constexpr (EPI == 0) {
          ((u16*)C0)[gr * (long)N + gc] = f2b(v);
        } else if constexpr (EPI == 1) {
          ((float*)C0)[gr * (long)N + gc] = tanhf(v + bias[gc]) * pw[gc];
        } else if constexpr (EPI == 2) {
          if (gr < M) ((float*)C0)[gr * (long)N + gc] = v + bias[gc];
        } else {  // EPI == 3
          if (gr < M) {
            long bb = gr & 31, tt = gr >> 5;
            float o = v + bias[gc];
            __builtin_nontemporal_store(o, &((float*)C0)[(bb * 31 + tt) * (long)N + gc]);
          }
        }
      }
}

// ---------------- per-step phase 1: uh + gh gates GEMV ----------------
// 256 blocks x 512 threads. Block owns 13 rows of Wcat (3328 = 256*13).
// tid -> b = tid>>4 (0..31), kc = tid&15 (k-chunk of 64).
__global__ __launch_bounds__(512)
void gates(const u16* __restrict__ Wcat, const u16* __restrict__ hbf,
           const float* __restrict__ bcat,
           float* __restrict__ uh, float* __restrict__ gh) {
  const int tid = threadIdx.x;
  const int b = tid >> 4;
  const int kc = tid & 15;
  const int r0 = blockIdx.x * 13;

  // preload h slice: 64 bf16 -> 64 f32 registers
  float hf[64];
  const u16* hp = hbf + b * 1024 + kc * 64;
#pragma unroll
  for (int j = 0; j < 8; ++j) {
    short8 hv = *(const short8*)(hp + j * 8);
#pragma unroll
    for (int e = 0; e < 8; ++e) hf[j * 8 + e] = b2f((u16)hv[e]);
  }

  for (int rr = 0; rr < 13; ++rr) {
    int r = r0 + rr;
    const u16* wr = Wcat + (long)r * 1024 + kc * 64;
    float p = 0.f;
#pragma unroll
    for (int j = 0; j < 8; ++j) {
      short8 wv = *(const short8*)(wr + j * 8);
#pragma unroll
      for (int e = 0; e < 8; ++e) p += b2f((u16)wv[e]) * hf[j * 8 + e];
    }
    p += __shfl_xor(p, 1);
    p += __shfl_xor(p, 2);
    p += __shfl_xor(p, 4);
    p += __shfl_xor(p, 8);
    if (kc == 0) {
      float val = p + bcat[r];
      if (r < 256) uh[b * 256 + r] = tanhf(val);
      else gh[(long)b * 3072 + (r - 256)] = val;
    }
  }
}

// ---------------- per-step phase 2: attention + gm + GRU combine ----------------
// 256 blocks = 32 b x 8 jc. Scores computed redundantly per jc (trivial).
__global__ __launch_bounds__(256)
void step2(const float* __restrict__ wvf,   // (4096, 256) f32
           const float* __restrict__ uh,    // (32, 256) f32
           const u16* __restrict__ FWb,     // (4096, 3072) bf16
           const float* __restrict__ GX,    // (992, 3072) f32, row t*32+b
           const float* __restrict__ gh,    // (32, 3072) f32
           const float* __restrict__ pb,
           float* __restrict__ h,           // (32, 1024) f32
           u16* __restrict__ hbf,           // (32, 1024) bf16
           u16* __restrict__ Hbuf,          // (1024, 1024) bf16, row t*32+b
           int t) {
  const int b = blockIdx.x >> 3;
  const int jc = blockIdx.x & 7;
  const int tid = threadIdx.x;
  __shared__ float uhl[256];
  __shared__ float part[256];
  __shared__ float attn[128];
  __shared__ float gmp[3][256];

  uhl[tid] = uh[b * 256 + tid];
  __syncthreads();

  // scores: s = tid&127, hf_ = tid>>7 handles half the 256 dims
  {
    const int s = tid & 127, hf_ = tid >> 7;
    const float* wr = wvf + ((long)(b * 128 + s)) * 256 + hf_ * 128;
    const float* u = &uhl[hf_ * 128];
    float p = 0.f;
#pragma unroll 8
    for (int d = 0; d < 128; d += 4) {
      float4 wv = *(const float4*)(wr + d);
      p += u[d] * wv.x + u[d + 1] * wv.y + u[d + 2] * wv.z + u[d + 3] * wv.w;
    }
    part[tid] = p;
  }
  __syncthreads();
  if (tid < 128) attn[tid] = part[tid] + part[tid + 128] + pb[0];
  __syncthreads();
  if (tid < 64) {
    float m = fmaxf(attn[tid], attn[tid + 64]);
#pragma unroll
    for (int o = 32; o; o >>= 1) m = fmaxf(m, __shfl_xor(m, o));
    float e0 = expf(attn[tid] - m), e1 = expf(attn[tid + 64] - m);
    float s2 = e0 + e1;
#pragma unroll
    for (int o = 32; o; o >>= 1) s2 += __shfl_xor(s2, o);
    float inv = 1.f / s2;
    attn[tid] = e0 * inv;
    attn[tid + 64] = e1 * inv;
  }
  __syncthreads();

  // gm triplets for cols {m, 1024+m, 2048+m}, m = jc*128 + ml
  {
    const int ml = tid & 127, half = tid >> 7;
    const int col = jc * 128 + ml;
    float g0 = 0.f, g1 = 0.f, g2 = 0.f;
    const u16* fw = FWb + ((long)(b * 128 + half * 64)) * 3072 + col;
#pragma unroll 4
    for (int s = 0; s < 64; ++s) {
      float a = attn[half * 64 + s];
      g0 += a * b2f(fw[0]);
      g1 += a * b2f(fw[1024]);
      g2 += a * b2f(fw[2048]);
      fw += 3072;
    }
    gmp[0][tid] = g0; gmp[1][tid] = g1; gmp[2][tid] = g2;
  }
  __syncthreads();

  if (tid < 128) {
    float gr_ = gmp[0][tid] + gmp[0][tid + 128];
    float gz_ = gmp[1][tid] + gmp[1][tid + 128];
    float gn_ = gmp[2][tid] + gmp[2][tid + 128];
    const int m = jc * 128 + tid;
    const long gxo = ((long)t * 32 + b) * 3072;
    float xr = GX[gxo + m] + gr_;
    float xz = GX[gxo + 1024 + m] + gz_;
    float xn = GX[gxo + 2048 + m] + gn_;
    float hr = gh[(long)b * 3072 + m];
    float hz = gh[(long)b * 3072 + 1024 + m];
    float hn = gh[(long)b * 3072 + 2048 + m];
    float r = 1.f / (1.f + expf(-(xr + hr)));
    float z = 1.f / (1.f + expf(-(xz + hz)));
    float n = tanhf(xn + r * hn);
    float hv = h[(long)b * 1024 + m];
    float h2 = (1.f - z) * n + z * hv;
    h[(long)b * 1024 + m] = h2;
    u16 hb_ = f2b(h2);
    hbf[b * 1024 + m] = hb_;
    Hbuf[((long)t * 32 + b) * 1024 + m] = hb_;
  }
}

// ---------------- launcher ----------------

extern "C" void kernel_launch(void* const* d_in, const int* in_sizes, int n_in,
                              void* d_out, int out_size, void* d_ws, size_t ws_size,
                              hipStream_t stream) {
  const float* f    = (const float*)d_in[0];   // (32,128,1024)
  const float* h0   = (const float*)d_in[1];   // (32,1024)
  const float* gt   = (const float*)d_in[2];   // (32,32,512)
  const float* U_w  = (const float*)d_in[4];   // (256,1024)
  const float* U_b  = (const float*)d_in[5];
  const float* V_w  = (const float*)d_in[6];   // (256,1024)
  const float* V_b  = (const float*)d_in[7];
  const float* P_w  = (const float*)d_in[8];   // (1,256)
  const float* P_b  = (const float*)d_in[9];
  const float* W_ih = (const float*)d_in[10];  // (3072,1536)
  const float* b_ih = (const float*)d_in[11];
  const float* W_hh = (const float*)d_in[12];  // (3072,1024)
  const float* b_hh = (const float*)d_in[13];
  const float* dw   = (const float*)d_in[14];  // (32000,1024)
  const float* db   = (const float*)d_in[15];

  char* w = (char*)d_ws;
  auto alloc = [&](size_t bytes) { char* p = w; w += (bytes + 255) & ~255ULL; return p; };

  u16*   fbf   = (u16*)alloc(4096L * 1024 * 2);   // f bf16, row b*128+s
  u16*   VwBf  = (u16*)alloc(256L * 1024 * 2);
  u16*   Wcat  = (u16*)alloc(3328L * 1024 * 2);   // [U_w; W_hh]
  u16*   WxBf  = (u16*)alloc(3072L * 512 * 2);    // W_ih[:, :512]
  u16*   WmBf  = (u16*)alloc(3072L * 1024 * 2);   // W_ih[:, 512:]
  u16*   dwBf  = (u16*)alloc(32000L * 1024 * 2);
  u16*   Xbf   = (u16*)alloc(1024L * 512 * 2);    // row t*32+b
  float* wvf   = (float*)alloc(4096L * 256 * 4);
  float* GX    = (float*)alloc(1024L * 3072 * 4);
  u16*   FWb   = (u16*)alloc(4096L * 3072 * 2);
  float* hf32  = (float*)alloc(32L * 1024 * 4);
  u16*   hbf   = (u16*)alloc(128L * 1024 * 2);
  float* uh    = (float*)alloc(32L * 256 * 4);
  float* ghb   = (float*)alloc(32L * 3072 * 4);
  u16*   Hbuf  = (u16*)alloc(1024L * 1024 * 2);
  float* bcat  = (float*)alloc(3328L * 4);        // [U_b; b_hh]

  auto cvg = [](long n) { long g = (n + 1023) / 1024; return (int)(g > 2048 ? 2048 : g); };

  // conversions / init
  cvt_flat<<<cvg(4194304), 256, 0, stream>>>(f, fbf, 4194304);
  cvt_flat<<<cvg(262144), 256, 0, stream>>>(V_w, VwBf, 262144);
  cvt_flat<<<cvg(262144), 256, 0, stream>>>(U_w, Wcat, 262144);
  cvt_flat<<<cvg(3145728), 256, 0, stream>>>(W_hh, Wcat + 262144L, 3145728);
  cvt_strided<<<2048, 256, 0, stream>>>(W_ih, WxBf, 3072L * 512, 9, 1536, 0);
  cvt_strided<<<2048, 256, 0, stream>>>(W_ih, WmBf, 3072L * 1024, 10, 1536, 512);
  cvt_flat<<<cvg(32768000), 256, 0, stream>>>(dw, dwBf, 32768000);
  cvt_x<<<2048, 256, 0, stream>>>(gt, Xbf);
  cvt_flat<<<cvg(32768), 256, 0, stream>>>(h0, hbf, 32768);
  hipMemcpyAsync(hf32, h0, 32L * 1024 * 4, hipMemcpyDeviceToDevice, stream);
  hipMemcpyAsync(bcat, U_b, 256 * 4, hipMemcpyDeviceToDevice, stream);
  hipMemcpyAsync(bcat + 256, b_hh, 3072 * 4, hipMemcpyDeviceToDevice, stream);

  // loop-invariant GEMMs
  gemm_bt<1><<<dim3(2, 32), 256, 0, stream>>>(fbf, VwBf, wvf, V_b, P_w, 4096, 256, 1024);
  gemm_bt<2><<<dim3(24, 8), 256, 0, stream>>>(Xbf, WxBf, GX, b_ih, nullptr, 992, 3072, 512);
  gemm_bt<0><<<dim3(24, 32), 256, 0, stream>>>(fbf, WmBf, FWb, nullptr, nullptr, 4096, 3072, 1024);

  // recurrence: 2 wide kernels per step
  for (int t = 0; t < 31; ++t) {
    gates<<<256, 512, 0, stream>>>(Wcat, hbf, bcat, uh, ghb);
    step2<<<256, 256, 0, stream>>>(wvf, uh, FWb, GX, ghb, P_b, hf32, hbf, Hbuf, t);
  }

  // logits
  gemm_bt<3><<<dim3(250, 8), 256, 0, stream>>>(Hbuf, dwBf, (float*)d_out, db, nullptr,
                                               992, 32000, 1024);
}